// Round 10
// baseline (1384.540 us; speedup 1.0000x reference)
//
#include <hip/hip_runtime.h>
#include <hip/hip_bf16.h>
#include <math.h>

// Problem constants
#define NPAT 4096
#define NKER 144
#define DIMC 512
#define QKV_N 1536
#define MLP_N 2048
#define R_TOT 8482      // 2*4096 + 2*144 + 2 rows (x | kx | clst)
#define R_PAD 8576      // padded to multiple of 128 for MFMA tiles
#define ROW_KX 8192
#define ROW_C 8480

typedef __hip_bfloat16 bf16;
using f32x4 = __attribute__((ext_vector_type(4))) float;
using s16x8 = __attribute__((ext_vector_type(8))) short;

template<typename T> __device__ __forceinline__ float tof(T v);
template<> __device__ __forceinline__ float tof<float>(float v) { return v; }
template<> __device__ __forceinline__ float tof<bf16>(bf16 v) { return __bfloat162float(v); }
template<typename T> __device__ __forceinline__ T fromf(float v);
template<> __device__ __forceinline__ float fromf<float>(float v) { return v; }
template<> __device__ __forceinline__ bf16 fromf<bf16>(float v) { return __float2bfloat16(v); }

// async global->LDS DMA, 16B per lane; LDS dest = wave-uniform base + lane*16
__device__ __forceinline__ void gload_lds16(const bf16* g, bf16* l) {
  __builtin_amdgcn_global_load_lds((const __attribute__((address_space(1))) void*)g,
                                   (__attribute__((address_space(3))) void*)l, 16, 0, 0);
}

// fast tanh-form GELU (max abs err ~3e-4 vs erf form)
__device__ __forceinline__ float gelu_f(float x) {
  float u = 0.7978845608028654f * (x + 0.044715f * x * x * x);
  float t = 2.f / (1.f + __expf(-2.f * u)) - 1.f;
  return 0.5f * x * (1.f + t);
}

// vectorized 64-dot: q = f32[64] (LDS), k = 64 contiguous bf16
__device__ __forceinline__ float dot64q(const float* __restrict__ q, const bf16* __restrict__ k) {
  float acc = 0.f;
  const uint4* k4 = (const uint4*)k;
  #pragma unroll
  for (int t = 0; t < 8; ++t) {
    union { uint4 u; bf16 h[8]; } w; w.u = k4[t];
    #pragma unroll
    for (int e = 0; e < 8; ++e) acc += q[t * 8 + e] * tof(w.h[e]);
  }
  return acc;
}

// ---------------- setup conversion ----------------
template<typename TD>
__global__ void cvt_in(const float* __restrict__ s, TD* __restrict__ d, int n) {
  int i = blockIdx.x * 256 + threadIdx.x;
  if (i < n) d[i] = fromf<TD>(s[i]);
}

// ---------------- per-batch mask max (for fully-masked-row detection) ----------------
__global__ __launch_bounds__(256) void pmax_calc(const float* __restrict__ pm,
                                                 float* __restrict__ pmax) {
  int b = blockIdx.x, t = threadIdx.x;
  float m = 0.f;
  for (int i = t; i < NPAT; i += 256) m = fmaxf(m, pm[(size_t)b * NPAT + i]);
  #pragma unroll
  for (int off = 32; off > 0; off >>= 1) m = fmaxf(m, __shfl_xor(m, off));
  __shared__ float ws[4];
  if ((t & 63) == 0) ws[t >> 6] = m;
  __syncthreads();
  if (t == 0) pmax[b] = fmaxf(fmaxf(ws[0], ws[1]), fmaxf(ws[2], ws[3]));
}

// ---------------- weight prep: f32 [K][N] -> bf16 [N][K] ----------------
__global__ __launch_bounds__(256) void transpose_cvt(const float* __restrict__ src,
    bf16* __restrict__ dst, int K, int N) {
  __shared__ float tile[32][33];
  int kb = blockIdx.y * 32, nb = blockIdx.x * 32;
  int tx = threadIdx.x & 31, ty = threadIdx.x >> 5;
  #pragma unroll
  for (int r = ty; r < 32; r += 8) tile[r][tx] = src[(size_t)(kb + r) * N + nb + tx];
  __syncthreads();
  #pragma unroll
  for (int r = ty; r < 32; r += 8)
    dst[(size_t)(nb + r) * K + kb + tx] = fromf<bf16>(tile[tx][r]);
}

// ---------------- fast LayerNorm: one wave per row, 4 rows/block ----------------
// src f32 [nrows x 512]; writes dst (TD) = LN result
template<typename TD>
__global__ __launch_bounds__(256) void ln_row4(const float* __restrict__ src,
    TD* __restrict__ dst, const float* __restrict__ g, const float* __restrict__ bb,
    int nrows) {
  int row = blockIdx.x * 4 + (threadIdx.x >> 6);
  if (row >= nrows) return;
  int lane = threadIdx.x & 63;
  const float4* p4 = (const float4*)(src + (size_t)row * DIMC);
  float4 a = p4[lane * 2], b = p4[lane * 2 + 1];
  float v[8] = {a.x, a.y, a.z, a.w, b.x, b.y, b.z, b.w};
  float s = 0.f;
  #pragma unroll
  for (int e = 0; e < 8; ++e) s += v[e];
  #pragma unroll
  for (int off = 32; off > 0; off >>= 1) s += __shfl_xor(s, off);
  float mean = s * (1.f / 512.f);
  float s2 = 0.f;
  #pragma unroll
  for (int e = 0; e < 8; ++e) { float d = v[e] - mean; s2 += d * d; }
  #pragma unroll
  for (int off = 32; off > 0; off >>= 1) s2 += __shfl_xor(s2, off);
  float rstd = rsqrtf(s2 * (1.f / 512.f) + 1e-5f);
  const float4* g4 = (const float4*)(g + lane * 8);
  const float4* b4 = (const float4*)(bb + lane * 8);
  float4 g0 = g4[0], g1 = g4[1], bb0 = b4[0], bb1 = b4[1];
  float gg[8] = {g0.x, g0.y, g0.z, g0.w, g1.x, g1.y, g1.z, g1.w};
  float bv[8] = {bb0.x, bb0.y, bb0.z, bb0.w, bb1.x, bb1.y, bb1.z, bb1.w};
  TD* q = dst + (size_t)row * DIMC + lane * 8;
  #pragma unroll
  for (int e = 0; e < 8; ++e) q[e] = fromf<TD>((v[e] - mean) * rstd * gg[e] + bv[e]);
}

// LN writing BOTH f32 in-place and bf16 copy; one wave/row
__global__ __launch_bounds__(256) void ln_dual4(float* __restrict__ act,
    bf16* __restrict__ actb, const float* __restrict__ g, const float* __restrict__ bb,
    int nrows) {
  int row = blockIdx.x * 4 + (threadIdx.x >> 6);
  if (row >= nrows) return;
  int lane = threadIdx.x & 63;
  float4* p4 = (float4*)(act + (size_t)row * DIMC);
  float4 a = p4[lane * 2], b = p4[lane * 2 + 1];
  float v[8] = {a.x, a.y, a.z, a.w, b.x, b.y, b.z, b.w};
  float s = 0.f;
  #pragma unroll
  for (int e = 0; e < 8; ++e) s += v[e];
  #pragma unroll
  for (int off = 32; off > 0; off >>= 1) s += __shfl_xor(s, off);
  float mean = s * (1.f / 512.f);
  float s2 = 0.f;
  #pragma unroll
  for (int e = 0; e < 8; ++e) { float d = v[e] - mean; s2 += d * d; }
  #pragma unroll
  for (int off = 32; off > 0; off >>= 1) s2 += __shfl_xor(s2, off);
  float rstd = rsqrtf(s2 * (1.f / 512.f) + 1e-5f);
  const float4* g4 = (const float4*)(g + lane * 8);
  const float4* b4 = (const float4*)(bb + lane * 8);
  float4 g0 = g4[0], g1 = g4[1], bb0 = b4[0], bb1 = b4[1];
  float gg[8] = {g0.x, g0.y, g0.z, g0.w, g1.x, g1.y, g1.z, g1.w};
  float bv[8] = {bb0.x, bb0.y, bb0.z, bb0.w, bb1.x, bb1.y, bb1.z, bb1.w};
  float r[8];
  #pragma unroll
  for (int e = 0; e < 8; ++e) r[e] = (v[e] - mean) * rstd * gg[e] + bv[e];
  p4[lane * 2]     = make_float4(r[0], r[1], r[2], r[3]);
  p4[lane * 2 + 1] = make_float4(r[4], r[5], r[6], r[7]);
  union { uint4 u; bf16 e[8]; } w;
  #pragma unroll
  for (int e = 0; e < 8; ++e) w.e[e] = fromf<bf16>(r[e]);
  *(uint4*)(actb + (size_t)row * DIMC + lane * 8) = w.u;
}

// ---------------- legacy LayerNorm (fallback path) ----------------
template<typename TS, typename TD>
__global__ __launch_bounds__(256) void ln_kernel(const TS* __restrict__ src,
    TD* __restrict__ dst, const float* __restrict__ g, const float* __restrict__ bb) {
  int row = blockIdx.x;
  const TS* p = src + (size_t)row * DIMC;
  int t = threadIdx.x;
  float v0 = tof(p[t]), v1 = tof(p[t + 256]);
  float s = v0 + v1;
  #pragma unroll
  for (int off = 32; off > 0; off >>= 1) s += __shfl_xor(s, off);
  __shared__ float ls[4], ls2[4];
  if ((t & 63) == 0) ls[t >> 6] = s;
  __syncthreads();
  float mean = (ls[0] + ls[1] + ls[2] + ls[3]) * (1.f / 512.f);
  float d0 = v0 - mean, d1 = v1 - mean;
  float s2 = d0 * d0 + d1 * d1;
  #pragma unroll
  for (int off = 32; off > 0; off >>= 1) s2 += __shfl_xor(s2, off);
  if ((t & 63) == 0) ls2[t >> 6] = s2;
  __syncthreads();
  float var = (ls2[0] + ls2[1] + ls2[2] + ls2[3]) * (1.f / 512.f);
  float rstd = rsqrtf(var + 1e-5f);
  TD* q = dst + (size_t)row * DIMC;
  q[t]       = fromf<TD>(d0 * rstd * g[t]       + bb[t]);
  q[t + 256] = fromf<TD>(d1 * rstd * g[t + 256] + bb[t + 256]);
}

// ---------------- MFMA GEMM v3: C[M,N] = A[M,K](bf16) @ Wt[N,K]^T (bf16) ----------------
template<int TM, typename TC, int ACT, bool HASRES>
__global__ __launch_bounds__(256) void gemm_mfma(
    const bf16* __restrict__ A, const bf16* __restrict__ Wt,
    const float* __restrict__ bias, const float* __restrict__ res,
    TC* __restrict__ C, int M, int N, int K) {
  constexpr int NI = 4;
  constexpr int NJ = (TM == 128) ? 4 : 2;
  constexpr int NQA = TM / 64;
  __shared__ bf16 As[2 * TM * 32];
  __shared__ bf16 Bs[2 * 128 * 32];
  int tid = threadIdx.x;
  int bm = blockIdx.y * TM, bn = blockIdx.x * 128;
  int wave = tid >> 6, lane = tid & 63;
  int quad = lane >> 4, lr = lane & 15;
  int WR = (TM == 128) ? (wave >> 1) * 64 : 0;
  int WC = (TM == 128) ? (wave & 1) * 64 : wave * 32;

  f32x4 acc[NI][NJ] = {};

  int rl = lane >> 2, pc = lane & 3;
  const bf16* aA[NQA]; const bf16* aB[2];
  int loA[NQA], loB[2];
  #pragma unroll
  for (int q = 0; q < NQA; ++q) {
    int rt = q * 64 + wave * 16 + rl;
    int c = pc ^ ((rt >> 1) & 3);
    aA[q] = A + (size_t)(bm + rt) * K + c * 8;
    loA[q] = (q * 64 + wave * 16) * 32;
  }
  #pragma unroll
  for (int q = 0; q < 2; ++q) {
    int rt = q * 64 + wave * 16 + rl;
    int c = pc ^ ((rt >> 1) & 3);
    aB[q] = Wt + (size_t)(bn + rt) * K + c * 8;
    loB[q] = (q * 64 + wave * 16) * 32;
  }

  auto stage = [&](int buf, int k0) {
    #pragma unroll
    for (int q = 0; q < NQA; ++q) gload_lds16(aA[q] + k0, As + buf * (TM * 32) + loA[q]);
    #pragma unroll
    for (int q = 0; q < 2; ++q)   gload_lds16(aB[q] + k0, Bs + buf * (128 * 32) + loB[q]);
  };

  stage(0, 0);
  int nk = K >> 5;
  for (int it = 0; it < nk; ++it) {
    __syncthreads();
    if (it + 1 < nk) stage((it + 1) & 1, (it + 1) << 5);
    const bf16* Ab = As + (it & 1) * (TM * 32);
    const bf16* Bb = Bs + (it & 1) * (128 * 32);
    s16x8 af[NI], bfr[NJ];
    #pragma unroll
    for (int i = 0; i < NI; ++i) {
      int ra = WR + i * 16 + lr;
      af[i] = *(const s16x8*)(Ab + ra * 32 + (quad ^ ((ra >> 1) & 3)) * 8);
    }
    #pragma unroll
    for (int j = 0; j < NJ; ++j) {
      int rb = WC + j * 16 + lr;
      bfr[j] = *(const s16x8*)(Bb + rb * 32 + (quad ^ ((rb >> 1) & 3)) * 8);
    }
    #pragma unroll
    for (int i = 0; i < NI; ++i)
      #pragma unroll
      for (int j = 0; j < NJ; ++j)
        acc[i][j] = __builtin_amdgcn_mfma_f32_16x16x32_bf16(af[i], bfr[j], acc[i][j], 0, 0, 0);
  }

  #pragma unroll
  for (int i = 0; i < NI; ++i) {
    int gm0 = bm + WR + i * 16 + quad * 4;
    #pragma unroll
    for (int j = 0; j < NJ; ++j) {
      int gn = bn + WC + j * 16 + lr;
      float bv = bias ? bias[gn] : 0.f;
      #pragma unroll
      for (int r = 0; r < 4; ++r) {
        int gm = gm0 + r;
        if (gm < M) {
          float v = acc[i][j][r] + bv;
          if (ACT == 1) v = gelu_f(v);
          if (HASRES) v += res[(size_t)gm * N + gn];
          C[(size_t)gm * N + gn] = fromf<TC>(v);
        }
      }
    }
  }
}

// ---------------- decay tables (per layer) ----------------
__global__ __launch_bounds__(256) void decay_tr(const float* __restrict__ rd,
    bf16* __restrict__ DT, bf16* __restrict__ DTk, float invden) {
  int ib = blockIdx.x * 32, jb = blockIdx.y * 32, b = blockIdx.z;
  __shared__ bf16 t[32][33];
  int tx = threadIdx.x & 31, ty = threadIdx.x >> 5;
  for (int r = ty; r < 32; r += 8) {
    int j = jb + r;
    if (j < NKER) {
      float v = rd[((size_t)b * NKER + j) * NPAT + ib + tx];
      bf16 dv = fromf<bf16>(__expf(-v * v * invden));
      t[r][tx] = dv;
      DTk[((size_t)b * NKER + j) * NPAT + ib + tx] = dv;
    }
  }
  __syncthreads();
  for (int r = ty; r < 32; r += 8) {
    int i = ib + r, j = jb + tx;
    if (j < NKER) DT[((size_t)b * NPAT + i) * NKER + j] = t[tx][r];
  }
}

// ---------------- fused patch->kernel attention (MFMA; softmax over j=144) ----------------
__global__ __launch_bounds__(256) void attn_p2k_f(
    const bf16* __restrict__ qkv, const float* __restrict__ pm,
    const float* __restrict__ km, const bf16* __restrict__ DT,
    bf16* __restrict__ o) {
  int i0 = blockIdx.x * 64, h = blockIdx.y, b = blockIdx.z;
  __shared__ bf16 Kk[144 * 72];
  __shared__ bf16 KvT[64 * 168];
  __shared__ bf16 Ps[64 * 168];     // phase 1 alias: Qs[64*72]
  __shared__ float pms[64];
  __shared__ float kms[144];
  int tid = threadIdx.x;
  bf16* Qs = Ps;

  for (int idx = tid; idx < 64 * 8; idx += 256) {
    int r = idx >> 3, c8 = idx & 7;
    *(uint4*)(Qs + r * 72 + c8 * 8) =
      *(const uint4*)(qkv + ((size_t)b * NPAT + i0 + r) * QKV_N + h * 64 + c8 * 8);
  }
  for (int idx = tid; idx < 144 * 8; idx += 256) {
    int r = idx >> 3, c8 = idx & 7;
    *(uint4*)(Kk + r * 72 + c8 * 8) =
      *(const uint4*)(qkv + ((size_t)ROW_KX + b * NKER + r) * QKV_N + DIMC + h * 64 + c8 * 8);
  }
  for (int idx = tid; idx < 144 * 8; idx += 256) {
    int r = idx >> 3, c8 = idx & 7;
    union { uint4 u; bf16 e[8]; } v;
    v.u = *(const uint4*)(qkv + ((size_t)ROW_KX + b * NKER + r) * QKV_N + 2 * DIMC + h * 64 + c8 * 8);
    #pragma unroll
    for (int e = 0; e < 8; ++e) KvT[(c8 * 8 + e) * 168 + r] = v.e[e];
  }
  for (int idx = tid; idx < 64 * 16; idx += 256) {
    int d = idx >> 4, j = 144 + (idx & 15);
    KvT[d * 168 + j] = fromf<bf16>(0.f);
  }
  if (tid < 64) pms[tid] = pm[(size_t)b * NPAT + i0 + tid];
  if (tid < 144) kms[tid] = km[b * NKER + tid];
  __syncthreads();

  int wave = tid >> 6, lane = tid & 63, quad = lane >> 4, lr = lane & 15;
  int mrow = wave * 16;

  f32x4 S[9] = {};
  #pragma unroll
  for (int kk = 0; kk < 64; kk += 32) {
    s16x8 a = *(const s16x8*)(Qs + (mrow + lr) * 72 + kk + quad * 8);
    #pragma unroll
    for (int n = 0; n < 9; ++n) {
      s16x8 bf_ = *(const s16x8*)(Kk + (n * 16 + lr) * 72 + kk + quad * 8);
      S[n] = __builtin_amdgcn_mfma_f32_16x16x32_bf16(a, bf_, S[n], 0, 0, 0);
    }
  }
  float mx[4] = {-3.4e38f, -3.4e38f, -3.4e38f, -3.4e38f};
  #pragma unroll
  for (int n = 0; n < 9; ++n) {
    int j = n * 16 + lr;
    float kmv = kms[j];
    #pragma unroll
    for (int r = 0; r < 4; ++r) {
      int il = mrow + quad * 4 + r;
      float s = S[n][r] * 0.125f;
      if (pms[il] * kmv < 0.5f) s = -1e9f;
      S[n][r] = s;
      mx[r] = fmaxf(mx[r], s);
    }
  }
  #pragma unroll
  for (int off = 1; off < 16; off <<= 1)
    #pragma unroll
    for (int r = 0; r < 4; ++r) mx[r] = fmaxf(mx[r], __shfl_xor(mx[r], off));
  float sum[4] = {0.f, 0.f, 0.f, 0.f};
  #pragma unroll
  for (int n = 0; n < 9; ++n)
    #pragma unroll
    for (int r = 0; r < 4; ++r) { float e = __expf(S[n][r] - mx[r]); S[n][r] = e; sum[r] += e; }
  #pragma unroll
  for (int off = 1; off < 16; off <<= 1)
    #pragma unroll
    for (int r = 0; r < 4; ++r) sum[r] += __shfl_xor(sum[r], off);
  float inv[4];
  #pragma unroll
  for (int r = 0; r < 4; ++r) inv[r] = 1.f / sum[r];
  #pragma unroll
  for (int n = 0; n < 9; ++n) {
    int j = n * 16 + lr;
    #pragma unroll
    for (int r = 0; r < 4; ++r) {
      int i = i0 + mrow + quad * 4 + r;
      S[n][r] = S[n][r] * inv[r] * tof(DT[((size_t)b * NPAT + i) * NKER + j]);
    }
  }
  __syncthreads();
  #pragma unroll
  for (int n = 0; n < 9; ++n) {
    int j = n * 16 + lr;
    #pragma unroll
    for (int r = 0; r < 4; ++r)
      Ps[(mrow + quad * 4 + r) * 168 + j] = fromf<bf16>(S[n][r]);
  }
  for (int idx = tid; idx < 64 * 16; idx += 256) {
    int rr = idx >> 4, j = 144 + (idx & 15);
    Ps[rr * 168 + j] = fromf<bf16>(0.f);
  }
  __syncthreads();
  f32x4 O[4] = {};
  #pragma unroll
  for (int kk = 0; kk < 160; kk += 32) {
    s16x8 a = *(const s16x8*)(Ps + (mrow + lr) * 168 + kk + quad * 8);
    #pragma unroll
    for (int nd = 0; nd < 4; ++nd) {
      s16x8 bf_ = *(const s16x8*)(KvT + (nd * 16 + lr) * 168 + kk + quad * 8);
      O[nd] = __builtin_amdgcn_mfma_f32_16x16x32_bf16(a, bf_, O[nd], 0, 0, 0);
    }
  }
  #pragma unroll
  for (int nd = 0; nd < 4; ++nd) {
    int d = nd * 16 + lr;
    #pragma unroll
    for (int r = 0; r < 4; ++r) {
      int i = i0 + mrow + quad * 4 + r;
      o[((size_t)b * NPAT + i) * DIMC + h * 64 + d] = fromf<bf16>(O[nd][r]);
    }
  }
}

// ---------------- k2p stage 1: P2b[b,h,j,i] = exp(s)*decay (bf16) + Z accumulation ------
// No max subtraction: |s| small for LN'd inputs. Fully-masked rows (km*pmax<0.5) -> e=1
// uniformly (matches reference's uniform softmax on all -1e9 rows).
__global__ __launch_bounds__(256) void s2p_gemm(
    const bf16* __restrict__ qkv, const float* __restrict__ pm,
    const float* __restrict__ km, const float* __restrict__ pmax,
    const bf16* __restrict__ DTk, bf16* __restrict__ P2b, float* __restrict__ Z) {
  int i0 = blockIdx.x * 128, h = blockIdx.y, b = blockIdx.z;
  __shared__ bf16 Kq[144 * 72];
  __shared__ bf16 Tk[128 * 72];
  __shared__ float pms[128];
  __shared__ float kms[144];
  int tid = threadIdx.x;
  for (int idx = tid; idx < 144 * 8; idx += 256) {
    int r = idx >> 3, c8 = idx & 7;
    *(uint4*)(Kq + r * 72 + c8 * 8) =
      *(const uint4*)(qkv + ((size_t)ROW_KX + b * NKER + r) * QKV_N + h * 64 + c8 * 8);
  }
  for (int idx = tid; idx < 128 * 8; idx += 256) {
    int r = idx >> 3, c8 = idx & 7;
    *(uint4*)(Tk + r * 72 + c8 * 8) =
      *(const uint4*)(qkv + ((size_t)b * NPAT + i0 + r) * QKV_N + DIMC + h * 64 + c8 * 8);
  }
  if (tid < 128) pms[tid] = pm[(size_t)b * NPAT + i0 + tid];
  if (tid < 144) kms[tid] = km[b * NKER + tid];
  __syncthreads();
  int wave = tid >> 6, lane = tid & 63, quad = lane >> 4, lr = lane & 15;
  int ncol = wave * 32;
  f32x4 acc[9][2] = {};
  #pragma unroll
  for (int kk = 0; kk < 64; kk += 32) {
    s16x8 bfr[2];
    #pragma unroll
    for (int ni = 0; ni < 2; ++ni)
      bfr[ni] = *(const s16x8*)(Tk + (ncol + ni * 16 + lr) * 72 + kk + quad * 8);
    #pragma unroll
    for (int mi = 0; mi < 9; ++mi) {
      s16x8 a = *(const s16x8*)(Kq + (mi * 16 + lr) * 72 + kk + quad * 8);
      #pragma unroll
      for (int ni = 0; ni < 2; ++ni)
        acc[mi][ni] = __builtin_amdgcn_mfma_f32_16x16x32_bf16(a, bfr[ni], acc[mi][ni], 0, 0, 0);
    }
  }
  int bh = b * 8 + h;
  size_t base = (size_t)bh * NKER * NPAT;
  float pmx = pmax[b];
  #pragma unroll
  for (int mi = 0; mi < 9; ++mi)
    #pragma unroll
    for (int r = 0; r < 4; ++r) {
      int j = mi * 16 + quad * 4 + r;
      float kmv = kms[j];
      bool fullmask = (kmv * pmx < 0.5f);
      float zpart = 0.f;
      #pragma unroll
      for (int ni = 0; ni < 2; ++ni) {
        int il = ncol + ni * 16 + lr;
        float s = acc[mi][ni][r] * 0.125f;
        float e;
        if (fullmask) e = 1.f;
        else if (pms[il] * kmv < 0.5f) e = 0.f;
        else e = __expf(s);
        zpart += e;
        float d = tof(DTk[((size_t)b * NKER + j) * NPAT + i0 + il]);
        P2b[base + (size_t)j * NPAT + i0 + il] = fromf<bf16>(e * d);
      }
      #pragma unroll
      for (int off = 1; off < 16; off <<= 1) zpart += __shfl_xor(zpart, off);
      if (lr == 0) atomicAdd(Z + (size_t)bh * NKER + j, zpart);
    }
}

// ---------------- k2p stage 2: pure split-K PV GEMM: koA += P2b @ V ----------------
__global__ __launch_bounds__(256) void pv_k2p(
    const bf16* __restrict__ P2b, const bf16* __restrict__ qkv,
    float* __restrict__ koA) {
  int kc = blockIdx.x, h = blockIdx.y, b = blockIdx.z;
  int tid = threadIdx.x;
  __shared__ char uls[144 * 64 * 4];
  bf16* TvT = (bf16*)uls;
  float* red = (float*)uls;
  int ib = kc * 256;
  for (int idx = tid; idx < 256 * 8; idx += 256) {
    int r = idx >> 3, c8 = idx & 7;
    union { uint4 u; bf16 e[8]; } v;
    v.u = *(const uint4*)(qkv + ((size_t)b * NPAT + ib + r) * QKV_N + 2 * DIMC + h * 64 + c8 * 8);
    #pragma unroll
    for (int e = 0; e < 8; ++e) TvT[(c8 * 8 + e) * 264 + r] = v.e[e];
  }
  __syncthreads();
  int wave = tid >> 6, lane = tid & 63, quad = lane >> 4, lr = lane & 15;
  int kb = wave * 64;
  int bh = b * 8 + h;
  size_t base = (size_t)bh * NKER * NPAT;
  f32x4 acc[9][4] = {};
  #pragma unroll
  for (int kk = 0; kk < 64; kk += 32) {
    s16x8 bfr[4];
    #pragma unroll
    for (int nd = 0; nd < 4; ++nd)
      bfr[nd] = *(const s16x8*)(TvT + (nd * 16 + lr) * 264 + kb + kk + quad * 8);
    #pragma unroll
    for (int mi = 0; mi < 9; ++mi) {
      s16x8 a = *(const s16x8*)(P2b + base + (size_t)(mi * 16 + lr) * NPAT + ib + kb + kk + quad * 8);
      #pragma unroll
      for (int nd = 0; nd < 4; ++nd)
        acc[mi][nd] = __builtin_amdgcn_mfma_f32_16x16x32_bf16(a, bfr[nd], acc[mi][nd], 0, 0, 0);
    }
  }
  __syncthreads();   // TvT dead; reuse as red
  for (int w = 0; w < 4; ++w) {
    if (wave == w) {
      #pragma unroll
      for (int mi = 0; mi < 9; ++mi)
        #pragma unroll
        for (int nd = 0; nd < 4; ++nd)
          #pragma unroll
          for (int r = 0; r < 4; ++r) {
            int j = mi * 16 + quad * 4 + r, d = nd * 16 + lr;
            if (w == 0) red[j * 64 + d] = acc[mi][nd][r];
            else        red[j * 64 + d] += acc[mi][nd][r];
          }
    }
    __syncthreads();
  }
  float* kbase = koA + (size_t)bh * NKER * 64;
  for (int idx = tid; idx < 144 * 64; idx += 256)
    atomicAdd(kbase + idx, red[idx]);
}

__global__ void merge_k2p(const float* __restrict__ koA, const float* __restrict__ Z,
                          bf16* __restrict__ o) {
  int idx = blockIdx.x * 256 + threadIdx.x;
  if (idx >= 2 * 8 * NKER * 64) return;
  int d = idx & 63, t = idx >> 6;
  int j = t % NKER; t /= NKER;
  int h = t & 7, b = t >> 3;
  float z = Z[(size_t)(b * 8 + h) * NKER + j];
  float v = (z > 0.f) ? koA[idx] / z : 0.f;
  o[((size_t)ROW_KX + b * NKER + j) * DIMC + h * 64 + d] = fromf<bf16>(v);
}

// ---------------- class token -> kernel attention ----------------
__global__ __launch_bounds__(64) void attn_c(const bf16* __restrict__ qkv,
    const float* __restrict__ pm, const float* __restrict__ km, bf16* __restrict__ o) {
  int h = blockIdx.x, b = blockIdx.y;
  int lane = threadIdx.x;
  size_t rowc = ROW_C + b;
  __shared__ float q_s[64];
  __shared__ float p_s[NKER];
  q_s[lane] = tof(qkv[rowc * QKV_N + h * 64 + lane]);
  __syncthreads();
  float pmv = pm[(size_t)b * NPAT];
  float lg[3];
  float mx = -3.4e38f;
  #pragma unroll
  for (int t = 0; t < 3; ++t) {
    int j = lane + t * 64;
    float val = -3.4e38f;
    if (j < NKER) {
      size_t rowk = ROW_KX + (size_t)b * NKER + j;
      float d = dot64q(q_s, qkv + rowk * QKV_N + DIMC + h * 64) * 0.125f;
      if (pmv * km[b * NKER + j] < 0.5f) d = -1e9f;
      val = d;
    }
    lg[t] = val;
    mx = fmaxf(mx, val);
  }
  #pragma unroll
  for (int off = 32; off > 0; off >>= 1) mx = fmaxf(mx, __shfl_xor(mx, off));
  float sum = 0.f, e[3];
  #pragma unroll
  for (int t = 0; t < 3; ++t) { e[t] = (lg[t] > -1e30f) ? __expf(lg[t] - mx) : 0.f; sum += e[t]; }
  #pragma unroll
  for (int off = 32; off > 0; off >>= 1) sum += __shfl_xor(sum, off);
  float inv = 1.f / sum;
  #pragma unroll
  for (int t = 0; t < 3; ++t) { int j = lane + t * 64; if (j < NKER) p_s[j] = e[t] * inv; }
  __syncthreads();
  const bf16* vb = qkv + (ROW_KX + (size_t)b * NKER) * QKV_N + 2 * DIMC + h * 64 + lane;
  float acc = 0.f;
  for (int j = 0; j < NKER; ++j) acc += p_s[j] * tof(vb[(size_t)j * QKV_N]);
  o[rowc * DIMC + h * 64 + lane] = fromf<bf16>(acc);
}

// ---------------- output emission (f32 out) ----------------
template<typename TS>
__global__ void emit_kreps(const TS* __restrict__ act, const float* __restrict__ km,
                           float* __restrict__ out, int l) {
  int idx = blockIdx.x * 256 + threadIdx.x;
  if (idx >= 2 * NKER * DIMC) return;
  int r = idx >> 9;
  float v = (km[r] < 0.5f) ? 0.f : tof(act[((size_t)ROW_KX + r) * DIMC + (idx & 511)]);
  out[(size_t)l * (2 * NKER * DIMC) + idx] = v;
}
template<typename TS>
__global__ void emit_clst(const TS* __restrict__ act, float* __restrict__ out) {
  int idx = blockIdx.x * 256 + threadIdx.x;
  if (idx >= 2 * DIMC) return;
  out[(size_t)4 * 2 * NKER * DIMC + idx] = tof(act[(size_t)ROW_C * DIMC + idx]);
}

// ---------------- legacy f32-VALU GEMM (deep fallback) ----------------
template<typename TA, typename TC>
__global__ __launch_bounds__(256) void gemm_bias(const TA* __restrict__ A,
    const float* __restrict__ W, const float* __restrict__ bias,
    const TC* __restrict__ res, TC* __restrict__ C,
    int M, int N, int K, int act) {
  __shared__ float As[16][64];
  __shared__ float Bs[16][64];
  int bm = blockIdx.y * 64, bn = blockIdx.x * 64;
  int tid = threadIdx.x;
  int tx = tid & 15, ty = tid >> 4;
  float acc[4][4] = {};
  for (int k0 = 0; k0 < K; k0 += 16) {
    #pragma unroll
    for (int it = 0; it < 4; ++it) {
      int idx = tid + 256 * it;
      int r = idx >> 4, c = idx & 15;
      int gm = bm + r;
      As[c][r] = (gm < M) ? tof(A[(size_t)gm * K + k0 + c]) : 0.f;
    }
    #pragma unroll
    for (int it = 0; it < 4; ++it) {
      int idx = tid + 256 * it;
      int r = idx >> 6, c = idx & 63;
      Bs[r][c] = W[(size_t)(k0 + r) * N + bn + c];
    }
    __syncthreads();
    #pragma unroll
    for (int kk = 0; kk < 16; ++kk) {
      float a[4], b[4];
      #pragma unroll
      for (int i = 0; i < 4; ++i) a[i] = As[kk][ty * 4 + i];
      #pragma unroll
      for (int j = 0; j < 4; ++j) b[j] = Bs[kk][tx * 4 + j];
      #pragma unroll
      for (int i = 0; i < 4; ++i)
        #pragma unroll
        for (int j = 0; j < 4; ++j) acc[i][j] += a[i] * b[j];
    }
    __syncthreads();
  }
  #pragma unroll
  for (int i = 0; i < 4; ++i) {
    int gm = bm + ty * 4 + i;
    if (gm >= M) continue;
    #pragma unroll
    for (int j = 0; j < 4; ++j) {
      int gn = bn + tx * 4 + j;
      float v = acc[i][j];
      if (bias) v += bias[gn];
      if (act == 1) v = gelu_f(v);
      if (res) v += tof(res[(size_t)gm * N + gn]);
      C[(size_t)gm * N + gn] = fromf<TC>(v);
    }
  }
}

// ---------------- fast2 pipeline (MFMA GEMM + MFMA attention) ----------------
static void run_fast2(void* const* d_in, float* out, float* act, bf16* actb,
                      bf16* bufo, bf16* bufq, bf16* wt,
                      float* S2, char* aux, float* koA, hipStream_t stream) {
  const float* x     = (const float*)d_in[0];
  const float* kx    = (const float*)d_in[1];
  const float* rd    = (const float*)d_in[2];
  const float* clst  = (const float*)d_in[3];
  const float* mask  = (const float*)d_in[4];
  const float* kmask = (const float*)d_in[5];
  const float* ln1g  = (const float*)d_in[6];
  const float* ln1b  = (const float*)d_in[7];
  const float* wqkv  = (const float*)d_in[8];
  const float* wout  = (const float*)d_in[9];
  const float* bout  = (const float*)d_in[10];
  const float* ln2g  = (const float*)d_in[11];
  const float* ln2b  = (const float*)d_in[12];
  const float* w1    = (const float*)d_in[13];
  const float* b1    = (const float*)d_in[14];
  const float* w2    = (const float*)d_in[15];
  const float* b2    = (const float*)d_in[16];

  // aux region (18.9 MB): Z | pmax | DT | DTk
  float* Zb   = (float*)aux;                               // 9216 B
  float* pmax = (float*)(aux + 16384);                     // 8 B
  bf16*  DT   = (bf16*)(aux + 32768);                      // 2.36 MB
  bf16*  DTk  = (bf16*)(aux + 32768 + (size_t)2 * NPAT * NKER * 2);  // 2.36 MB
  bf16*  P2b  = (bf16*)S2;                                 // 18.9 MB, aliases S2/ffh region

  bf16* wtq = wt;
  bf16* wto = wtq + (size_t)4 * QKV_N * DIMC;
  bf16* wt1 = wto + (size_t)4 * DIMC * DIMC;
  bf16* wt2 = wt1 + (size_t)4 * MLP_N * DIMC;

  for (int l = 0; l < 4; ++l) {
    transpose_cvt<<<dim3(QKV_N / 32, DIMC / 32), 256, 0, stream>>>(
        wqkv + (size_t)l * DIMC * QKV_N, wtq + (size_t)l * QKV_N * DIMC, DIMC, QKV_N);
    transpose_cvt<<<dim3(DIMC / 32, DIMC / 32), 256, 0, stream>>>(
        wout + (size_t)l * DIMC * DIMC, wto + (size_t)l * DIMC * DIMC, DIMC, DIMC);
    transpose_cvt<<<dim3(MLP_N / 32, DIMC / 32), 256, 0, stream>>>(
        w1 + (size_t)l * DIMC * MLP_N, wt1 + (size_t)l * MLP_N * DIMC, DIMC, MLP_N);
    transpose_cvt<<<dim3(DIMC / 32, MLP_N / 32), 256, 0, stream>>>(
        w2 + (size_t)l * MLP_N * DIMC, wt2 + (size_t)l * DIMC * MLP_N, MLP_N, DIMC);
  }
  pmax_calc<<<2, 256, 0, stream>>>(mask, pmax);

  bf16* qkv  = bufq;               // R_PAD x 1536
  bf16* ffh  = (bf16*)S2;          // R_PAD x 2048 aliases S2 (disjoint lifetimes within a layer)
  bf16* o    = bufo;
  bf16* actn = bufo;

  cvt_in<float><<<(2 * NPAT * DIMC + 255) / 256, 256, 0, stream>>>(x, act, 2 * NPAT * DIMC);
  cvt_in<float><<<(2 * NKER * DIMC + 255) / 256, 256, 0, stream>>>(kx, act + (size_t)ROW_KX * DIMC, 2 * NKER * DIMC);
  cvt_in<float><<<(2 * DIMC + 255) / 256, 256, 0, stream>>>(clst, act + (size_t)ROW_C * DIMC, 2 * DIMC);

  const int MT = R_PAD / 128;    // 67
  const int MT64 = R_PAD / 64;   // 134
  const int KON = 2 * 8 * NKER * 64;
  const int LNB = (R_TOT + 3) / 4;

  for (int l = 0; l < 4; ++l) {
    float invden = 1.0f / (64.0f * (float)(1 << l));
    ln_dual4<<<LNB, 256, 0, stream>>>(act, actb, ln1g + l * DIMC, ln1b + l * DIMC, R_TOT);
    gemm_mfma<128, bf16, 0, false><<<dim3(QKV_N / 128, MT), 256, 0, stream>>>(
        actb, wtq + (size_t)l * QKV_N * DIMC, nullptr, nullptr, qkv, R_TOT, QKV_N, DIMC);
    // attention (MFMA path)
    decay_tr<<<dim3(NPAT / 32, 5, 2), 256, 0, stream>>>(rd, DT, DTk, invden);
    attn_p2k_f<<<dim3(NPAT / 64, 8, 2), 256, 0, stream>>>(qkv, mask, kmask, DT, o);
    hipMemsetAsync(Zb, 0, 2 * 8 * NKER * 4, stream);
    hipMemsetAsync(koA, 0, (size_t)KON * 4, stream);
    s2p_gemm<<<dim3(NPAT / 128, 8, 2), 256, 0, stream>>>(qkv, mask, kmask, pmax, DTk, P2b, Zb);
    pv_k2p<<<dim3(16, 8, 2), 256, 0, stream>>>(P2b, qkv, koA);
    merge_k2p<<<(KON + 255) / 256, 256, 0, stream>>>(koA, Zb, o);
    attn_c<<<dim3(8, 2), 64, 0, stream>>>(qkv, mask, kmask, o);
    // out projection + residual (TM=64 for occupancy)
    gemm_mfma<64, float, 0, true><<<dim3(DIMC / 128, MT64), 256, 0, stream>>>(
        o, wto + (size_t)l * DIMC * DIMC, bout + l * DIMC, act, act, R_TOT, DIMC, DIMC);
    // FFN — un-chunked (ffh aliases S2/P2b; both dead after pv)
    ln_row4<bf16><<<LNB, 256, 0, stream>>>(act, actn, ln2g + l * DIMC, ln2b + l * DIMC, R_TOT);
    gemm_mfma<128, bf16, 1, false><<<dim3(MLP_N / 128, MT), 256, 0, stream>>>(
        actn, wt1 + (size_t)l * MLP_N * DIMC, b1 + l * MLP_N, nullptr, ffh, R_TOT, MLP_N, DIMC);
    gemm_mfma<64, float, 0, true><<<dim3(DIMC / 128, MT64), 256, 0, stream>>>(
        ffh, wt2 + (size_t)l * DIMC * MLP_N, b2 + l * DIMC, act, act, R_TOT, DIMC, MLP_N);
    emit_kreps<float><<<(2 * NKER * DIMC + 255) / 256, 256, 0, stream>>>(act, kmask, out, l);
  }
  emit_clst<float><<<(2 * DIMC + 255) / 256, 256, 0, stream>>>(act, out);
}

// ---------------- legacy pipeline (deep fallback, f32 VALU) ----------------
template<typename ActT>
static void run_pipeline(void* const* d_in, float* out, ActT* act, bf16* bufo, bf16* bufq,
                         hipStream_t stream) {
  const float* x     = (const float*)d_in[0];
  const float* kx    = (const float*)d_in[1];
  const float* clst  = (const float*)d_in[3];
  const float* mask  = (const float*)d_in[4];
  const float* kmask = (const float*)d_in[5];
  const float* ln1g  = (const float*)d_in[6];
  const float* ln1b  = (const float*)d_in[7];
  const float* wqkv  = (const float*)d_in[8];
  const float* wout  = (const float*)d_in[9];
  const float* bout  = (const float*)d_in[10];
  const float* ln2g  = (const float*)d_in[11];
  const float* ln2b  = (const float*)d_in[12];
  const float* w1    = (const float*)d_in[13];
  const float* b1    = (const float*)d_in[14];
  const float* w2    = (const float*)d_in[15];
  const float* b2    = (const float*)d_in[16];

  bf16* qkv  = bufq;
  bf16* ffh  = bufq;
  bf16* o    = bufo;
  bf16* actn = bufo;
  const int FF_CHUNK = 4241;

  cvt_in<ActT><<<(2 * NPAT * DIMC + 255) / 256, 256, 0, stream>>>(x, act, 2 * NPAT * DIMC);
  cvt_in<ActT><<<(2 * NKER * DIMC + 255) / 256, 256, 0, stream>>>(kx, act + (size_t)ROW_KX * DIMC, 2 * NKER * DIMC);
  cvt_in<ActT><<<(2 * DIMC + 255) / 256, 256, 0, stream>>>(clst, act + (size_t)ROW_C * DIMC, 2 * DIMC);

  for (int l = 0; l < 4; ++l) {
    ln_kernel<ActT, ActT><<<R_TOT, 256, 0, stream>>>(act, act, ln1g + l * DIMC, ln1b + l * DIMC);
    gemm_bias<ActT, bf16><<<dim3(QKV_N / 64, (R_TOT + 63) / 64), 256, 0, stream>>>(
        act, wqkv + (size_t)l * DIMC * QKV_N, nullptr, nullptr, qkv, R_TOT, QKV_N, DIMC, 0);
    attn_c<<<dim3(8, 2), 64, 0, stream>>>(qkv, mask, kmask, o);
    gemm_bias<bf16, ActT><<<dim3(DIMC / 64, (R_TOT + 63) / 64), 256, 0, stream>>>(
        o, wout + (size_t)l * DIMC * DIMC, bout + l * DIMC, act, act, R_TOT, DIMC, DIMC, 0);
    ln_kernel<ActT, bf16><<<R_TOT, 256, 0, stream>>>(act, actn, ln2g + l * DIMC, ln2b + l * DIMC);
    for (int c0 = 0; c0 < R_TOT; c0 += FF_CHUNK) {
      int rows = (R_TOT - c0 < FF_CHUNK) ? (R_TOT - c0) : FF_CHUNK;
      gemm_bias<bf16, bf16><<<dim3(MLP_N / 64, (rows + 63) / 64), 256, 0, stream>>>(
          actn + (size_t)c0 * DIMC, w1 + (size_t)l * DIMC * MLP_N, b1 + l * MLP_N,
          nullptr, ffh, rows, MLP_N, DIMC, 1);
      gemm_bias<bf16, ActT><<<dim3(DIMC / 64, (rows + 63) / 64), 256, 0, stream>>>(
          ffh, w2 + (size_t)l * MLP_N * DIMC, b2 + l * DIMC,
          act + (size_t)c0 * DIMC, act + (size_t)c0 * DIMC, rows, DIMC, MLP_N, 0);
    }
    emit_kreps<ActT><<<(2 * NKER * DIMC + 255) / 256, 256, 0, stream>>>(act, kmask, out, l);
  }
  emit_clst<ActT><<<(2 * DIMC + 255) / 256, 256, 0, stream>>>(act, out);
}

// ---------------- host entry ----------------
extern "C" void kernel_launch(void* const* d_in, const int* in_sizes, int n_in,
                              void* d_out, int out_size, void* d_ws, size_t ws_size,
                              hipStream_t stream) {
  (void)in_sizes; (void)n_in; (void)out_size;
  float* out = (float*)d_out;

  const size_t szA  = (size_t)R_TOT * DIMC * 4;
  const size_t szAB = (size_t)R_PAD * DIMC * 2;
  const size_t szO  = (size_t)R_PAD * DIMC * 2;
  const size_t szQ  = (size_t)R_PAD * QKV_N * 2;
  const size_t szW  = (size_t)4 * (QKV_N * DIMC + DIMC * DIMC + MLP_N * DIMC + DIMC * MLP_N) * 2;
  const size_t szS2 = (size_t)2 * 8 * NKER * NPAT * 4;   // 37.75 MB: P2b (18.9) / ffh (35.1)
  const size_t szAux = (size_t)2 * 8 * NKER * NPAT * 2;  // 18.87 MB: Z/pmax/DT/DTk
  const size_t szKo = (size_t)2 * 8 * NKER * 64 * 4;     //  0.59 MB
  const size_t needFast2 = szA + szAB + szO + szQ + szW + szS2 + szAux + szKo;

  if (ws_size >= needFast2) {
    char* w = (char*)d_ws;
    float* act  = (float*)w;            w += szA;
    bf16*  actb = (bf16*)w;             w += szAB;
    bf16*  bufo = (bf16*)w;             w += szO;
    bf16*  bufq = (bf16*)w;             w += szQ;
    bf16*  wt   = (bf16*)w;             w += szW;
    float* S2   = (float*)w;            w += szS2;
    char*  aux  = w;                    w += szAux;
    float* koA  = (float*)w;
    run_fast2(d_in, out, act, actb, bufo, bufq, wt, S2, aux, koA, stream);
  } else if (ws_size >= szA + szO + szQ) {
    float* act = (float*)d_ws;
    bf16* bufo = (bf16*)((char*)d_ws + szA);
    bf16* bufq = (bf16*)((char*)d_ws + szA + szO);
    run_pipeline<float>(d_in, out, act, bufo, bufq, stream);
  } else {
    bf16* act = (bf16*)d_ws;
    bf16* bufo = (bf16*)((char*)d_ws + szO);
    bf16* bufq = (bf16*)((char*)d_ws + 2 * szO);
    run_pipeline<bf16>(d_in, out, act, bufo, bufq, stream);
  }
}